// Round 16
// baseline (37.948 us; speedup 1.0000x reference)
//
#include <hip/hip_runtime.h>

#define FH 128
#define FW 128
#define CPLANE 490                 // 10*7*7 input channels; plane c_in serves bin (ph,pw)
#define NBATCH 4
#define NPLANES (NBATCH * CPLANE)  // 1960 = 8 * 245
#define SSCALE 0.0625f
#define PLFL (FH * FW)             // floats per plane (16384)

// ws layout (ints, proven-safe band): [0..3]=counts, [4 + b*R + slot]=roi idx
#define WS_CNT  0
#define WS_LIST 4

typedef float f32x4 __attribute__((ext_vector_type(4)));

// ---- kernel A: one block per batch; ballot-compaction, zero atomics --------
__global__ __launch_bounds__(1024) void bucket_rois(const float* __restrict__ rois,
                                                    int R, int* __restrict__ ws) {
    __shared__ int wtot[16];
    const int b   = blockIdx.x;
    const int tid = threadIdx.x;

    const int i0 = tid * 2, i1 = i0 + 1;
    const bool m0 = (i0 < R) && ((int)rois[(size_t)i0 * 5] == b);
    const bool m1 = (i1 < R) && ((int)rois[(size_t)i1 * 5] == b);
    const unsigned long long bl0 = __ballot(m0);
    const unsigned long long bl1 = __ballot(m1);
    const int w    = tid >> 6;
    const int lane = tid & 63;
    const unsigned long long below = ((unsigned long long)1 << lane) - 1;
    if (lane == 0) wtot[w] = __popcll(bl0) + __popcll(bl1);
    __syncthreads();

    int nb = 0, woff = 0;
#pragma unroll
    for (int ww = 0; ww < 16; ++ww) {
        const int c = wtot[ww];
        if (ww < w) woff += c;
        nb += c;
    }
    const int p0 = woff + __popcll(bl0 & below) + __popcll(bl1 & below);
    if (m0) ws[WS_LIST + b * R + p0] = i0;
    if (m1) ws[WS_LIST + b * R + p0 + (m0 ? 1 : 0)] = i1;
    if (tid == 0) ws[WS_CNT + b] = nb;
}

// register-free async global->LDS (16B per lane); cannot be sunk by regalloc
__device__ __forceinline__ void gload_lds16(const float* g, float* l) {
    __builtin_amdgcn_global_load_lds(
        (const __attribute__((address_space(1))) void*)g,
        (__attribute__((address_space(3))) void*)l,
        16, 0, 0);
}

// ---- kernel B: persistent, DMA double-buffered plane pipeline ---------------
// 1 block/CU, 128KB dynamic LDS (2x64KB). Per plane: barrier (vmcnt(0) =>
// DMA of current buffer complete) -> issue next plane's DMA into other
// buffer -> gather current. The HBM read stream never idles.
__global__ __launch_bounds__(1024) void psroi_dma(const float* __restrict__ feat,
                                                  const float* __restrict__ rois,
                                                  const int* __restrict__ ws,
                                                  float* __restrict__ out, int R) {
    extern __shared__ float dbuf[];            // 2 * 16384 floats
    const int tid = threadIdx.x;
    const int bid = blockIdx.x;
    const int xcd = bid & 7;                   // XCD chunking preserved (write-merge)
    const int j   = bid >> 3;                  // 0..31 within XCD
    const int np  = (j < 21) ? 8 : 7;          // 245 = 32*7 + 21 planes per XCD chunk
    const int pl0 = xcd * (NPLANES / 8) + j;   // planes pl0 + 32*i, all same batch

    const int b     = pl0 / CPLANE;
    const int  nb   = ws[WS_CNT + b];
    const int* list = ws + WS_LIST + b * R;

    const int   sub = tid & 3;                 // bilinear sample id
    const float sy  = 0.25f + 0.5f * (float)(sub >> 1);
    const float sx  = 0.25f + 0.5f * (float)(sub & 1);

    // prologue: DMA plane pl0 into buffer 0
    {
        const float* src = feat + (size_t)pl0 * PLFL;
#pragma unroll
        for (int c = 0; c < 4; ++c)
            gload_lds16(src + c * 4096 + tid * 4, dbuf + c * 4096 + tid * 4);
    }

    int cur = 0;
    for (int i = 0; i < np; ++i) {
        asm volatile("s_waitcnt vmcnt(0)" ::: "memory");  // buf[cur] DMA complete
        __syncthreads();                                   // + prev gather done

        if (i + 1 < np) {                  // issue next plane's DMA now (drains under gather)
            const float* srcn = feat + (size_t)(pl0 + 32 * (i + 1)) * PLFL;
            float* ldst = dbuf + (cur ^ 1) * PLFL;
#pragma unroll
            for (int c = 0; c < 4; ++c)
                gload_lds16(srcn + c * 4096 + tid * 4, ldst + c * 4096 + tid * 4);
        }

        // ---- gather current plane ----
        const int pl    = pl0 + 32 * i;
        const int c_in  = pl - b * CPLANE;
        const int pw    = c_in % 7;
        const int ph    = (c_in / 7) % 7;
        const float* pb = dbuf + cur * PLFL;

        for (int base = 0; base < nb; base += 256) {
            const int k = base + (tid >> 2);
            if (k < nb) {
                const int ri = list[k];
                const float* roi = rois + (size_t)ri * 5;   // hot 40 KB, cache-resident
                const float x1 = roi[1] * SSCALE;
                const float y1 = roi[2] * SSCALE;
                const float bw = fmaxf(roi[3] * SSCALE - x1, 0.1f) * (1.0f / 7.0f);
                const float bh = fmaxf(roi[4] * SSCALE - y1, 0.1f) * (1.0f / 7.0f);

                float y = y1 + ((float)ph + sy) * bh;
                y = fminf(fmaxf(y, 0.0f), 127.0f);
                float y0f = floorf(y);
                int   y0  = (int)y0f;
                float ly  = y - y0f;
                if (y0 > 126) { y0 = 126; ly = 1.0f; }   // y==127 -> full weight row 127

                float x = x1 + ((float)pw + sx) * bw;
                x = fminf(fmaxf(x, 0.0f), 127.0f);
                float x0f = floorf(x);
                int   x0  = (int)x0f;
                float lx  = x - x0f;
                if (x0 > 126) { x0 = 126; lx = 1.0f; }

                const float* p = pb + y0 * FW + x0;
                const float v00 = p[0];
                const float v01 = p[1];
                const float v10 = p[FW];
                const float v11 = p[FW + 1];

                const float top = v00 + (v01 - v00) * lx;
                const float bot = v10 + (v11 - v10) * lx;
                float val = top + (bot - top) * ly;

                val += __shfl_xor(val, 1);
                val += __shfl_xor(val, 2);
                if (sub == 0) out[(size_t)ri * CPLANE + c_in] = val * 0.25f;
            }
        }
        cur ^= 1;
    }
}

extern "C" void kernel_launch(void* const* d_in, const int* in_sizes, int n_in,
                              void* d_out, int out_size, void* d_ws, size_t ws_size,
                              hipStream_t stream) {
    const float* feat = (const float*)d_in[0];
    const float* rois = (const float*)d_in[1];
    float* out = (float*)d_out;
    int* ws = (int*)d_ws;

    const int R = in_sizes[1] / 5;   // 2048

    static bool attr_set = false;    // host-side, idempotent, capture-safe
    if (!attr_set) {
        hipFuncSetAttribute((const void*)psroi_dma,
                            hipFuncAttributeMaxDynamicSharedMemorySize, 2 * PLFL * 4);
        attr_set = true;
    }

    bucket_rois<<<NBATCH, 1024, 0, stream>>>(rois, R, ws);
    psroi_dma<<<256, 1024, 2 * PLFL * 4, stream>>>(feat, rois, ws, out, R);
}

// Round 17
// 35.059 us; speedup vs baseline: 1.0824x; 1.0824x over previous
//
#include <hip/hip_runtime.h>

#define FH 128
#define FW 128
#define CPLANE 490                 // 10*7*7 input channels; plane c_in serves bin (ph,pw)
#define NBATCH 4
#define NPLANES (NBATCH * CPLANE)  // 1960 = 8 * 245
#define NBLK (NPLANES * 2)         // 3920 (plane x half)
#define SSCALE 0.0625f
#define YSPLIT 60.0f               // lo < 60 -> top half
#define RB_BOT 58                  // bottom stages rows 58..127 (2-row FP margin)
#define NR_TOP 64
#define NR_BOT 70

// ws layout (ints), total 5892 ints = 23.6 KB (proven-safe band)
#define WS_CNT  0                  // [0..3] per-batch roi count
#define WS_LIST 4                  // ushort list[b*2048+pos], 4096 ints
#define WS_MASK 4100               // u64 mask[(b*7+ph)*32 + word], 1792 ints

typedef float f32x4 __attribute__((ext_vector_type(4)));
typedef unsigned long long u64;
typedef unsigned short u16;

// ---- kernel A: bucket (ushort list) + per-(b,ph) top-half bitmask ----------
// Thread t handles roi indices t and t+1024 so ballot words map directly to
// mask words. Zero atomics (round 11 lesson).
__global__ __launch_bounds__(1024) void bucket_rois(const float* __restrict__ rois,
                                                    int R, int* __restrict__ ws) {
    __shared__ int wtot[16];
    const int b    = blockIdx.x;
    const int tid  = threadIdx.x;
    const int w    = tid >> 6;
    const int lane = tid & 63;
    const u64 below = ((u64)1 << lane) - 1;

    u16* list16 = (u16*)(ws + WS_LIST) + b * 2048;
    u64* mask   = (u64*)(ws + WS_MASK) + b * 7 * 32;

    const int i0 = tid, i1 = tid + 1024;
    bool  m0 = false, m1 = false;
    float lo0[7], lo1[7];
    if (i0 < R && (int)rois[(size_t)i0 * 5] == b) {
        m0 = true;
        const float y1 = rois[(size_t)i0 * 5 + 2] * SSCALE;
        const float bh = fmaxf(rois[(size_t)i0 * 5 + 4] * SSCALE - y1, 0.1f) * (1.0f / 7.0f);
#pragma unroll
        for (int p = 0; p < 7; ++p) lo0[p] = y1 + ((float)p + 0.25f) * bh;
    }
    if (i1 < R && (int)rois[(size_t)i1 * 5] == b) {
        m1 = true;
        const float y1 = rois[(size_t)i1 * 5 + 2] * SSCALE;
        const float bh = fmaxf(rois[(size_t)i1 * 5 + 4] * SSCALE - y1, 0.1f) * (1.0f / 7.0f);
#pragma unroll
        for (int p = 0; p < 7; ++p) lo1[p] = y1 + ((float)p + 0.25f) * bh;
    }

    // membership masks: word w covers indices 64w..64w+63; word 16+w the +1024 range
#pragma unroll
    for (int p = 0; p < 7; ++p) {
        const u64 t0 = __ballot(m0 && (lo0[p] < YSPLIT));
        const u64 t1 = __ballot(m1 && (lo1[p] < YSPLIT));
        if (lane == 0) { mask[p * 32 + w] = t0; mask[p * 32 + 16 + w] = t1; }
    }

    // ushort list compaction (order irrelevant, deterministic)
    const u64 bl0 = __ballot(m0);
    const u64 bl1 = __ballot(m1);
    if (lane == 0) wtot[w] = __popcll(bl0) + __popcll(bl1);
    __syncthreads();
    int nb = 0, woff = 0;
#pragma unroll
    for (int ww = 0; ww < 16; ++ww) {
        const int c = wtot[ww];
        if (ww < w) woff += c;
        nb += c;
    }
    if (m0) list16[woff + __popcll(bl0 & below)] = (u16)i0;
    if (m1) list16[woff + __popcll(bl0) + __popcll(bl1 & below)] = (u16)i1;
    if (tid == 0) ws[WS_CNT + b] = nb;
}

// ---- kernel B: one block per (plane, half); 512 thr, ~39KB LDS -> 4/CU ------
// 4 alternating stage/gather processes per CU tile the HBM pipe (idle prob
// ~(G/(S+G))^4 ~1%). Block compacts its half's rois via mask bit (no
// geometry recompute, no wasted gather iterations).
__global__ __launch_bounds__(512, 8) void psroi_half(const float* __restrict__ feat,
                                                     const float* __restrict__ rois,
                                                     const int* __restrict__ ws,
                                                     float* __restrict__ out, int R) {
    __shared__ float plane[NR_BOT * FW];   // 35840 B (max of 64/70 rows)
    __shared__ u16   clist[2048];
    __shared__ int   wtot[8];

    const int tid  = threadIdx.x;
    const int bid  = blockIdx.x;
    const int xcd  = bid & 7;              // XCD chunking: siblings same XCD (write-merge)
    const int j    = bid >> 3;             // 0..489
    const int pl   = xcd * 245 + (j >> 1);
    const int half = j & 1;
    const int b    = pl / CPLANE;
    const int c_in = pl - b * CPLANE;
    const int pw   = c_in % 7;
    const int ph   = (c_in / 7) % 7;
    const int rbase = half ? RB_BOT : 0;
    const int nq    = (half ? NR_BOT : NR_TOP) * (FW / 4);   // 2240 / 2048 float4s

    // ---- phase 0: issue staging loads (plain: L2-cached; R15 lesson) ----
    const f32x4* __restrict__ src = (const f32x4*)(feat + (size_t)pl * (FH * FW)) + rbase * (FW / 4);
    f32x4 s0 = src[0 * 512 + tid];
    f32x4 s1 = src[1 * 512 + tid];
    f32x4 s2 = src[2 * 512 + tid];
    f32x4 s3 = src[3 * 512 + tid];
    f32x4 s4;
    const bool p4 = (2048 + tid) < nq;
    if (p4) s4 = src[2048 + tid];

    // ---- phase 1: compact this half's rois from ushort list + mask bit ----
    const int  nb     = ws[WS_CNT + b];
    const u16* list16 = (const u16*)(ws + WS_LIST) + b * 2048;
    const u64* mask   = (const u64*)(ws + WS_MASK) + (b * 7 + ph) * 32;
    const bool want   = (half == 0);       // bit==1 means top half

    const int w    = tid >> 6;
    const int lane = tid & 63;
    const u64 below = ((u64)1 << lane) - 1;

    bool m[4]; int ridx[4]; u64 bl[4];
#pragma unroll
    for (int q = 0; q < 4; ++q) {
        const int k = q * 512 + tid;
        bool mm = false; int ri = 0;
        if (k < nb) {
            ri = list16[k];
            mm = ((mask[ri >> 6] >> (ri & 63)) & 1ull) == (want ? 1ull : 0ull);
        }
        m[q] = mm; ridx[q] = ri; bl[q] = __ballot(mm);
    }
    if (lane == 0)
        wtot[w] = __popcll(bl[0]) + __popcll(bl[1]) + __popcll(bl[2]) + __popcll(bl[3]);
    __syncthreads();

    int nbh = 0, woff = 0;
#pragma unroll
    for (int ww = 0; ww < 8; ++ww) {
        const int c = wtot[ww];
        if (ww < w) woff += c;
        nbh += c;
    }
    int pos = woff;
#pragma unroll
    for (int q = 0; q < 4; ++q) {
        if (m[q]) clist[pos + __popcll(bl[q] & below)] = (u16)ridx[q];
        pos += __popcll(bl[q]);
    }

    // ---- phase 2: commit staged rows to LDS ----
    *(f32x4*)(plane + (0 * 512 + tid) * 4) = s0;
    *(f32x4*)(plane + (1 * 512 + tid) * 4) = s1;
    *(f32x4*)(plane + (2 * 512 + tid) * 4) = s2;
    *(f32x4*)(plane + (3 * 512 + tid) * 4) = s3;
    if (p4) *(f32x4*)(plane + (2048 + tid) * 4) = s4;
    __syncthreads();

    // ---- phase 3: gather, 4 lanes per roi, exactly nbh entries ----
    const int   sub = tid & 3;
    const float sy  = 0.25f + 0.5f * (float)(sub >> 1);
    const float sx  = 0.25f + 0.5f * (float)(sub & 1);

    for (int base = 0; base < nbh; base += 128) {
        const int k = base + (tid >> 2);
        if (k < nbh) {
            const int ri = clist[k];
            const float* roi = rois + (size_t)ri * 5;   // hot 40 KB, cache-resident
            const float x1 = roi[1] * SSCALE;
            const float y1 = roi[2] * SSCALE;
            const float bw = fmaxf(roi[3] * SSCALE - x1, 0.1f) * (1.0f / 7.0f);
            const float bh = fmaxf(roi[4] * SSCALE - y1, 0.1f) * (1.0f / 7.0f);

            float y = y1 + ((float)ph + sy) * bh;
            y = fminf(fmaxf(y, 0.0f), 127.0f);
            float y0f = floorf(y);
            int   y0  = (int)y0f;
            float ly  = y - y0f;
            if (y0 > 126) { y0 = 126; ly = 1.0f; }   // y==127 -> full weight on row 127

            float x = x1 + ((float)pw + sx) * bw;
            x = fminf(fmaxf(x, 0.0f), 127.0f);
            float x0f = floorf(x);
            int   x0  = (int)x0f;
            float lx  = x - x0f;
            if (x0 > 126) { x0 = 126; lx = 1.0f; }

            const float* p = plane + (y0 - rbase) * FW + x0;
            const float v00 = p[0];
            const float v01 = p[1];
            const float v10 = p[FW];
            const float v11 = p[FW + 1];

            const float top = v00 + (v01 - v00) * lx;
            const float bot = v10 + (v11 - v10) * lx;
            float val = top + (bot - top) * ly;

            val += __shfl_xor(val, 1);
            val += __shfl_xor(val, 2);
            if (sub == 0) out[(size_t)ri * CPLANE + c_in] = val * 0.25f;
        }
    }
}

extern "C" void kernel_launch(void* const* d_in, const int* in_sizes, int n_in,
                              void* d_out, int out_size, void* d_ws, size_t ws_size,
                              hipStream_t stream) {
    const float* feat = (const float*)d_in[0];
    const float* rois = (const float*)d_in[1];
    float* out = (float*)d_out;
    int* ws = (int*)d_ws;

    const int R = in_sizes[1] / 5;   // 2048

    bucket_rois<<<NBATCH, 1024, 0, stream>>>(rois, R, ws);
    psroi_half<<<NBLK, 512, 0, stream>>>(feat, rois, ws, out, R);
}

// Round 18
// 32.575 us; speedup vs baseline: 1.1649x; 1.0763x over previous
//
#include <hip/hip_runtime.h>

#define FH 128
#define FW 128
#define CPLANE 490                 // 10*7*7 input channels; plane c_in serves bin (ph,pw)
#define NBATCH 4
#define NPLANES (NBATCH * CPLANE)  // 1960 = 8 * 245
#define SSCALE 0.0625f

typedef float f32x4 __attribute__((ext_vector_type(4)));

// Single fused kernel: one plane per block (XCD-chunked), self-built roi list.
// R13 structure with PLAIN staging loads (R14->R15 A/B: NT costs ~2us).
// Phases: issue loads -> ballot-compact roi list in LDS (overlaps load
// latency) -> lift list to regs -> commit plane to LDS -> gather.
__global__ __launch_bounds__(1024, 8) void psroi_fused(const float* __restrict__ feat,
                                                       const float* __restrict__ rois,
                                                       float* __restrict__ out, int R) {
    __shared__ float plane[FH * FW];           // exactly 64 KB -> 2 blocks/CU
    int* const lint = (int*)plane;             // compacted roi list (ints 0..2047)
    int* const wtot = (int*)plane + (FH * FW - 16);  // 16 per-wave counts (tail region)

    const int tid = threadIdx.x;
    const int bid = blockIdx.x;
    const int pl  = (bid & 7) * (NPLANES / 8) + (bid >> 3);  // bijective XCD chunking
    const int b    = pl / CPLANE;
    const int c_in = pl - b * CPLANE;
    const int pw   = c_in % 7;
    const int ph   = (c_in / 7) % 7;

    // ---- phase 0: issue full-plane PLAIN loads; in flight through the scan ----
    const f32x4* __restrict__ src = (const f32x4*)(feat + (size_t)pl * (FH * FW));
    f32x4 s0 = src[0 * 1024 + tid];
    f32x4 s1 = src[1 * 1024 + tid];
    f32x4 s2 = src[2 * 1024 + tid];
    f32x4 s3 = src[3 * 1024 + tid];

    // ---- phase 1: scan rois (2/thread), deterministic ballot compaction ----
    const int i0 = tid * 2, i1 = i0 + 1;
    bool m0 = false, m1 = false;
    if (i0 < R) m0 = ((int)rois[(size_t)i0 * 5] == b);
    if (i1 < R) m1 = ((int)rois[(size_t)i1 * 5] == b);
    const unsigned long long bl0 = __ballot(m0);
    const unsigned long long bl1 = __ballot(m1);
    const int w    = tid >> 6;
    const int lane = tid & 63;
    const unsigned long long below = ((unsigned long long)1 << lane) - 1;
    if (lane == 0) wtot[w] = __popcll(bl0) + __popcll(bl1);
    __syncthreads();

    int nb = 0, woff = 0;
#pragma unroll
    for (int ww = 0; ww < 16; ++ww) {
        const int c = wtot[ww];
        if (ww < w) woff += c;
        nb += c;
    }
    const int p0 = woff + __popcll(bl0 & below) + __popcll(bl1 & below);
    if (m0) lint[p0] = i0;
    if (m1) lint[p0 + (m0 ? 1 : 0)] = i1;
    __syncthreads();

    // ---- phase 2: lift my <=8 gather entries into named regs (rule #20) ----
    const int kb = tid >> 2;
    const int r0 = lint[kb];
    const int r1 = lint[kb + 256];
    const int r2 = lint[kb + 512];
    const int r3 = lint[kb + 768];
    const int r4 = lint[kb + 1024];
    const int r5 = lint[kb + 1280];
    const int r6 = lint[kb + 1536];
    const int r7 = lint[kb + 1792];
    __syncthreads();                 // list fully consumed; plane may overwrite

    // ---- phase 3: commit staged plane to LDS (vmcnt wait lands here) ----
    *(f32x4*)(plane + (0 * 1024 + tid) * 4) = s0;
    *(f32x4*)(plane + (1 * 1024 + tid) * 4) = s1;
    *(f32x4*)(plane + (2 * 1024 + tid) * 4) = s2;
    *(f32x4*)(plane + (3 * 1024 + tid) * 4) = s3;
    __syncthreads();

    // ---- phase 4: gather, 4 lanes per roi ----
    const int   sub = tid & 3;
    const float sy  = 0.25f + 0.5f * (float)(sub >> 1);
    const float sx  = 0.25f + 0.5f * (float)(sub & 1);

    auto gather = [&](int k, int ri) {
        if (k < nb) {
            const float* roi = rois + (size_t)ri * 5;   // hot 40 KB, cache-resident
            const float x1 = roi[1] * SSCALE;
            const float y1 = roi[2] * SSCALE;
            const float bw = fmaxf(roi[3] * SSCALE - x1, 0.1f) * (1.0f / 7.0f);
            const float bh = fmaxf(roi[4] * SSCALE - y1, 0.1f) * (1.0f / 7.0f);

            float y = y1 + ((float)ph + sy) * bh;
            y = fminf(fmaxf(y, 0.0f), 127.0f);
            float y0f = floorf(y);
            int   y0  = (int)y0f;
            float ly  = y - y0f;
            if (y0 > 126) { y0 = 126; ly = 1.0f; }   // y==127 -> full weight on row 127

            float x = x1 + ((float)pw + sx) * bw;
            x = fminf(fmaxf(x, 0.0f), 127.0f);
            float x0f = floorf(x);
            int   x0  = (int)x0f;
            float lx  = x - x0f;
            if (x0 > 126) { x0 = 126; lx = 1.0f; }

            const float* p = plane + y0 * FW + x0;
            const float v00 = p[0];
            const float v01 = p[1];
            const float v10 = p[FW];
            const float v11 = p[FW + 1];

            const float top = v00 + (v01 - v00) * lx;
            const float bot = v10 + (v11 - v10) * lx;
            float val = top + (bot - top) * ly;

            val += __shfl_xor(val, 1);
            val += __shfl_xor(val, 2);
            if (sub == 0) out[(size_t)ri * CPLANE + c_in] = val * 0.25f;
        }
    };
    gather(kb,        r0);
    gather(kb + 256,  r1);
    gather(kb + 512,  r2);
    gather(kb + 768,  r3);
    gather(kb + 1024, r4);
    gather(kb + 1280, r5);
    gather(kb + 1536, r6);
    gather(kb + 1792, r7);
}

extern "C" void kernel_launch(void* const* d_in, const int* in_sizes, int n_in,
                              void* d_out, int out_size, void* d_ws, size_t ws_size,
                              hipStream_t stream) {
    const float* feat = (const float*)d_in[0];
    const float* rois = (const float*)d_in[1];
    float* out = (float*)d_out;

    const int R = in_sizes[1] / 5;   // 2048 (kernel assumes R <= 2048)

    psroi_fused<<<NPLANES, 1024, 0, stream>>>(feat, rois, out, R);
}